// Round 3
// baseline (80932.825 us; speedup 1.0000x reference)
//
#include <hip/hip_runtime.h>
#include <hip/hip_bf16.h>

static constexpr int Bsz  = 256;   // batch
static constexpr int Tseq = 256;   // timesteps
static constexpr int Hd   = 512;   // d_model
static constexpr int Ein  = 64;    // enc_in

typedef __attribute__((ext_vector_type(8))) short bf16x8;
typedef __attribute__((ext_vector_type(4))) float f32x4;

struct Params {
  const float* x;                     // [B, T, Ein] fp32
  float *Hm1, *Hm2, *Hcur, *Nst;      // h_{t-1}, h_{t-2}, h_t, N (fp32 state)
  float *zA, *NrA, *s1, *score, *Omega, *mbuf, *zM, *mrM;
  float* out_hidden;                  // [B, T, Hd] fp32
  int t;
};

__device__ __forceinline__ float sigm(float x) { return 1.f / (1.f + expf(-x)); }
__device__ __forceinline__ short f2bf(float f) {   // RN-even fp32 -> bf16 bits
  union { float f; unsigned u; } v; v.f = f;
  unsigned r = v.u + 0x7FFFu + ((v.u >> 16) & 1u);
  return (short)(r >> 16);
}
__device__ __forceinline__ float bf2f(short s) {
  union { float f; unsigned u; } v; v.u = ((unsigned)(unsigned short)s) << 16; return v.f;
}

enum { A_DT, A_WS, A_X };
enum { E_GATEA, E_NNEW, E_S1, E_SCORE, E_M, E_GATEM, E_HNEW };

// ---------------------------------------------------------------------------
// Weight prepack: fp32 [K][N] -> fragment-major bf16 hi/lo.
// Packed layout per matrix: for k-chunk kc (32 rows), n-tile ntg (16 cols):
//   elem(lane, j) = W[kc*32 + (lane>>4)*8 + j][ntg*16 + (lane&15)]
//   at offset ((kc*(N/16) + ntg)*64 + lane)*8 + j.
// Each MFMA B-fragment is then ONE coalesced 16B load per lane.
// ---------------------------------------------------------------------------
__global__ __launch_bounds__(256)
void prepack(const float* __restrict__ W, short* __restrict__ Whi,
             short* __restrict__ Wlo, int N)
{
  __shared__ float lds[32][257];
  const int tid = threadIdx.x;
  const int k0 = blockIdx.y * 32;
  const int n0 = blockIdx.x * 256;
  #pragma unroll
  for (int i = 0; i < 8; ++i) {
    const int flat = (i * 256 + tid) * 4;       // 32x256 stripe
    const int r = flat >> 8, c = flat & 255;
    const float4 v = *(const float4*)(W + (size_t)(k0 + r) * N + n0 + c);
    lds[r][c] = v.x; lds[r][c + 1] = v.y; lds[r][c + 2] = v.z; lds[r][c + 3] = v.w;
  }
  __syncthreads();
  const int lane = tid & 63, wv = tid >> 6;
  const int kr = (lane >> 4) * 8;
  const int cc = lane & 15;
  for (int nt = wv; nt < 16; nt += 4) {
    const int ntg = (n0 >> 4) + nt;
    const size_t off = ((size_t)((k0 >> 5) * (N >> 4) + ntg) * 64 + lane) * 8;
    bf16x8 vh, vl;
    #pragma unroll
    for (int j = 0; j < 8; ++j) {
      const float v = lds[kr + j][nt * 16 + cc];
      const short hb = f2bf(v);
      vh[j] = hb; vl[j] = f2bf(v - bf2f(hb));
    }
    *(bf16x8*)(Whi + off) = vh;
    *(bf16x8*)(Wlo + off) = vl;
  }
}

// ---------------------------------------------------------------------------
// MFMA dual-GEMM: C = A1@W1 [+ A2@W2] (+bias) with fused epilogue.
// BM=32, BN=128, BK=32; 256 thr = 4 waves (2x2), wave = 16x64 (4 n-frags).
// A (fp32) split bf16 hi/lo in LDS; W pre-packed hi/lo fragment-major.
// 3 MFMAs per fragment: Ah*Wh + Al*Wh + Ah*Wl  (~fp24 effective precision).
// ---------------------------------------------------------------------------
template<int A1M, int K1, int K2, int NC, int EPI>
__global__ __launch_bounds__(256)
void gemm_mfma(Params p,
               const short* __restrict__ Whi1, const short* __restrict__ Wlo1,
               const short* __restrict__ Whi2, const short* __restrict__ Wlo2,
               const float* __restrict__ bias,
               const float* __restrict__ A1, const float* __restrict__ A1b,
               const float* __restrict__ A2)
{
  __shared__ short Ahi[32][40], Alo[32][40];   // stride 80B: 16B-aligned rows, ~2-way banks
  const int tid = threadIdx.x;
  const int mb = blockIdx.y * 32;
  const int nb = blockIdx.x * 128;
  const int lane = tid & 63, wv = tid >> 6;
  const int wm = wv >> 1, wn = wv & 1;
  const int sr = tid >> 3;            // staging row 0..31
  const int sc = (tid & 7) << 2;      // staging k base (x4)
  const int ar = wm * 16 + (lane & 15);
  const int ak = (lane >> 4) * 8;

  f32x4 acc[4];
  #pragma unroll
  for (int i = 0; i < 4; ++i) acc[i] = (f32x4){0.f, 0.f, 0.f, 0.f};

  #pragma unroll
  for (int pass = 0; pass < 2; ++pass) {
    const int KT = pass ? K2 : K1;
    const short* Whi = pass ? Whi2 : Whi1;
    const short* Wlo = pass ? Wlo2 : Wlo1;
    for (int kb = 0; kb < KT; kb += 32) {
      float a0, a1, a2, a3;
      if (pass == 0 && A1M == A_X) {
        const float4 u = *(const float4*)(p.x + (size_t)(mb + sr) * (Tseq * Ein) + p.t * Ein + kb + sc);
        a0 = u.x; a1 = u.y; a2 = u.z; a3 = u.w;
      } else if (pass == 0 && A1M == A_DT) {
        const float4 u = *(const float4*)(A1 + (mb + sr) * Hd + kb + sc);
        const float4 v = *(const float4*)(A1b + (mb + sr) * Hd + kb + sc);
        a0 = u.x - v.x; a1 = u.y - v.y; a2 = u.z - v.z; a3 = u.w - v.w;
      } else {
        const float* A = pass ? A2 : A1;
        const float4 u = *(const float4*)(A + (mb + sr) * Hd + kb + sc);
        a0 = u.x; a1 = u.y; a2 = u.z; a3 = u.w;
      }
      const float av[4] = {a0, a1, a2, a3};
      #pragma unroll
      for (int i = 0; i < 4; ++i) {
        const short hb = f2bf(av[i]);
        Ahi[sr][sc + i] = hb;
        Alo[sr][sc + i] = f2bf(av[i] - bf2f(hb));
      }
      __syncthreads();

      const bf16x8 ah = *(const bf16x8*)&Ahi[ar][ak];
      const bf16x8 al = *(const bf16x8*)&Alo[ar][ak];
      const int kc = kb >> 5;
      #pragma unroll
      for (int nt = 0; nt < 4; ++nt) {
        const int ntg = (nb >> 4) + wn * 4 + nt;
        const size_t off = ((size_t)(kc * (NC >> 4) + ntg) * 64 + lane) * 8;
        const bf16x8 bh = *(const bf16x8*)(Whi + off);
        const bf16x8 bl = *(const bf16x8*)(Wlo + off);
        acc[nt] = __builtin_amdgcn_mfma_f32_16x16x32_bf16(ah, bh, acc[nt], 0, 0, 0);
        acc[nt] = __builtin_amdgcn_mfma_f32_16x16x32_bf16(al, bh, acc[nt], 0, 0, 0);
        acc[nt] = __builtin_amdgcn_mfma_f32_16x16x32_bf16(ah, bl, acc[nt], 0, 0, 0);
      }
      __syncthreads();
    }
  }

  // Epilogue: D[row][col]: col = lane&15 (+n-tile base), row = (lane>>4)*4 + r.
  #pragma unroll
  for (int nt = 0; nt < 4; ++nt) {
    const int col = nb + wn * 64 + nt * 16 + (lane & 15);
    #pragma unroll
    for (int r = 0; r < 4; ++r) {
      const int row = mb + wm * 16 + (lane >> 4) * 4 + r;
      float g = acc[nt][r];
      if (bias) g += bias[col];
      if constexpr (EPI == E_GATEA) {
        const float s = sigm(g);
        if (col < Hd) p.zA[row * Hd + col] = s;
        else { const int j = col - Hd; p.NrA[row * Hd + j] = p.Nst[row * Hd + j] * s; }
      } else if constexpr (EPI == E_NNEW) {
        const float hn = tanhf(g);
        const float z  = p.zA[row * Hd + col];
        const float No = p.Nst[row * Hd + col];
        p.Nst[row * Hd + col] = (1.f - z) * No + z * hn;
      } else if constexpr (EPI == E_S1) {
        p.s1[row * Hd + col] = tanhf(g);
      } else if constexpr (EPI == E_SCORE) {
        p.score[row * Hd + col] = g;
      } else if constexpr (EPI == E_M) {
        p.mbuf[row * Hd + col] = tanhf(g);
      } else if constexpr (EPI == E_GATEM) {
        const float s = sigm(g);
        if (col < Hd) p.zM[row * Hd + col] = s;
        else { const int j = col - Hd; p.mrM[row * Hd + j] = p.mbuf[row * Hd + j] * s; }
      } else if constexpr (EPI == E_HNEW) {
        const float hh = tanhf(g);
        const float z  = p.zM[row * Hd + col];
        const float hp = p.Hm1[row * Hd + col];
        const float hnew = (1.f - z) * hp + z * hh;
        p.Hcur[row * Hd + col] = hnew;
        p.out_hidden[((size_t)row * Tseq + p.t) * Hd + col] = hnew;
      }
    }
  }
}

// One block per batch row: softmax over Hd=512, Omega = alpha * N_new.
__global__ __launch_bounds__(256)
void softmax_omega(Params p)
{
  __shared__ float red[256];
  const int b = blockIdx.x, tid = threadIdx.x;
  const float* sc = p.score + b * Hd;
  const float v0 = sc[tid], v1 = sc[tid + 256];
  red[tid] = fmaxf(v0, v1);
  __syncthreads();
  for (int s = 128; s > 0; s >>= 1) {
    if (tid < s) red[tid] = fmaxf(red[tid], red[tid + s]);
    __syncthreads();
  }
  const float mx = red[0];
  __syncthreads();
  const float e0 = expf(v0 - mx), e1 = expf(v1 - mx);
  red[tid] = e0 + e1;
  __syncthreads();
  for (int s = 128; s > 0; s >>= 1) {
    if (tid < s) red[tid] += red[tid + s];
    __syncthreads();
  }
  const float inv = 1.f / red[0];
  p.Omega[b * Hd + tid]       = e0 * inv * p.Nst[b * Hd + tid];
  p.Omega[b * Hd + tid + 256] = e1 * inv * p.Nst[b * Hd + tid + 256];
}

__global__ __launch_bounds__(256)
void init_state(float* h1, float* h2, float* n) {
  const int i = blockIdx.x * 256 + threadIdx.x;
  h1[i] = 0.f; h2[i] = 0.f; n[i] = 0.f;
}

__global__ __launch_bounds__(256)
void finalize(const float* __restrict__ hT, const float* __restrict__ nT,
              float* __restrict__ oh, float* __restrict__ on) {
  const int i = blockIdx.x * 256 + threadIdx.x;
  oh[i] = hT[i]; on[i] = nT[i];
}

extern "C" void kernel_launch(void* const* d_in, const int* in_sizes, int n_in,
                              void* d_out, int out_size, void* d_ws, size_t ws_size,
                              hipStream_t stream)
{
  (void)in_sizes; (void)n_in; (void)out_size; (void)ws_size;
  const float* x   = (const float*)d_in[0];
  const float* ba  = (const float*)d_in[3];
  const float* bna = (const float*)d_in[6];
  const float* bma = (const float*)d_in[12];
  const float* bm  = (const float*)d_in[15];
  const float* bhm = (const float*)d_in[18];

  float* w = (float*)d_ws;
  const int S = Bsz * Hd;               // 131072 floats per state buffer
  float* Hb[3] = { w, w + S, w + 2 * S };

  Params p{};
  p.x = x;
  p.Nst = w + 3 * S;  p.zA = w + 4 * S;  p.NrA = w + 5 * S;  p.s1 = w + 6 * S;
  p.score = w + 7 * S; p.Omega = w + 8 * S; p.mbuf = w + 9 * S;
  p.zM = w + 10 * S;  p.mrM = w + 11 * S;
  float* out = (float*)d_out;
  p.out_hidden = out;
  float* out_hT = out + (size_t)Bsz * Tseq * Hd;
  float* out_NT = out_hT + S;

  // ---- packed weight region (bf16 hi/lo), after fp32 scratch ----
  short* wpk = (short*)(w + 12 * S);
  // order: Wa,Ua,Wna,Una,WAt,UAt,VAt,Wma,Uma,Wm,Um,Whm,Uhm (d_in idx / K / N)
  const int widx[13] = {1, 2, 4, 5, 7, 8, 9, 10, 11, 13, 14, 16, 17};
  const int wK[13]   = {512, 512, 512, 512, 512, 512, 512, 512, 512, 64, 512, 64, 512};
  const int wN[13]   = {1024, 1024, 512, 512, 512, 512, 512, 512, 512, 1024, 1024, 512, 512};
  short *Whi[13], *Wlo[13];
  {
    size_t off = 0;
    for (int i = 0; i < 13; ++i) {
      const size_t sz = (size_t)wK[i] * wN[i];
      Whi[i] = wpk + off;       off += sz;
      Wlo[i] = wpk + off;       off += sz;
    }
  }
  for (int i = 0; i < 13; ++i) {
    dim3 g(wN[i] / 256, wK[i] / 32);
    prepack<<<g, 256, 0, stream>>>((const float*)d_in[widx[i]], Whi[i], Wlo[i], wN[i]);
  }

  init_state<<<S / 256, 256, 0, stream>>>(Hb[1], Hb[2], p.Nst);

  const dim3 blk(256);
  const dim3 g512(4, 8);     // N=512: 4 n-tiles x 8 m-tiles
  const dim3 g1024(8, 8);    // N=1024

  for (int t = 0; t < Tseq; ++t) {
    Params q = p;
    q.t = t;
    q.Hcur = Hb[t % 3];
    q.Hm1  = Hb[(t + 2) % 3];
    q.Hm2  = Hb[(t + 1) % 3];
    // gates_A = d_t@Wa + N@Ua + ba -> z_A, NrA
    gemm_mfma<A_DT, 512, 512, 1024, E_GATEA><<<g1024, blk, 0, stream>>>(
        q, Whi[0], Wlo[0], Whi[1], Wlo[1], ba, q.Hm1, q.Hm2, q.Nst);
    // hat_N = tanh(d_t@Wna + NrA@Una + bna); N <- (1-z)N + z hat_N
    gemm_mfma<A_DT, 512, 512, 512, E_NNEW><<<g512, blk, 0, stream>>>(
        q, Whi[2], Wlo[2], Whi[3], Wlo[3], bna, q.Hm1, q.Hm2, q.NrA);
    // s1 = tanh(h@WAttn + N_new@UAttn)
    gemm_mfma<A_WS, 512, 512, 512, E_S1><<<g512, blk, 0, stream>>>(
        q, Whi[4], Wlo[4], Whi[5], Wlo[5], nullptr, q.Hm1, nullptr, q.Nst);
    // score = s1 @ VAttn
    gemm_mfma<A_WS, 512, 0, 512, E_SCORE><<<g512, blk, 0, stream>>>(
        q, Whi[6], Wlo[6], nullptr, nullptr, nullptr, q.s1, nullptr, nullptr);
    // alpha = softmax(score); Omega = alpha * N_new
    softmax_omega<<<Bsz, blk, 0, stream>>>(q);
    // m = tanh(Omega@Wma + h@Uma + bma)
    gemm_mfma<A_WS, 512, 512, 512, E_M><<<g512, blk, 0, stream>>>(
        q, Whi[7], Wlo[7], Whi[8], Wlo[8], bma, q.Omega, nullptr, q.Hm1);
    // gates_M = x_t@Wm + m@Um + bm -> z_M, mrM
    gemm_mfma<A_X, 64, 512, 1024, E_GATEM><<<g1024, blk, 0, stream>>>(
        q, Whi[9], Wlo[9], Whi[10], Wlo[10], bm, nullptr, nullptr, q.mbuf);
    // hat_h = tanh(x_t@Whm + mrM@Uhm + bhm); h_t = (1-z_M)h + z_M hat_h
    gemm_mfma<A_X, 64, 512, 512, E_HNEW><<<g512, blk, 0, stream>>>(
        q, Whi[11], Wlo[11], Whi[12], Wlo[12], bhm, nullptr, nullptr, q.mrM);
  }
  finalize<<<S / 256, 256, 0, stream>>>(Hb[(Tseq - 1) % 3], p.Nst, out_hT, out_NT);
}

// Round 5
// 33379.813 us; speedup vs baseline: 2.4246x; 2.4246x over previous
//
#include <hip/hip_runtime.h>

static constexpr int Bsz  = 256;   // batch
static constexpr int Tseq = 256;   // timesteps
static constexpr int Hd   = 512;   // d_model
static constexpr int Ein  = 64;    // enc_in
static constexpr int NBLK = 256;   // persistent blocks (1 per CU)
static constexpr int NTHR = 512;   // 8 waves per block

typedef __attribute__((ext_vector_type(8))) short bf16x8;
typedef __attribute__((ext_vector_type(4))) float f32x4;
typedef unsigned long long u64;

__device__ __forceinline__ float sigm(float x) { return 1.f / (1.f + expf(-x)); }
__device__ __forceinline__ short f2bf(float f) {   // RN-even fp32 -> bf16 bits
  union { float f; unsigned u; } v; v.f = f;
  unsigned r = v.u + 0x7FFFu + ((v.u >> 16) & 1u);
  return (short)(r >> 16);
}
__device__ __forceinline__ float bf2f(short s) {
  union { float f; unsigned u; } v; v.u = ((unsigned)(unsigned short)s) << 16; return v.f;
}
__device__ __forceinline__ u64 pk(short a, short b, short c, short d) {
  return (u64)(unsigned short)a | ((u64)(unsigned short)b << 16)
       | ((u64)(unsigned short)c << 32) | ((u64)(unsigned short)d << 48);
}

struct KP {
  const float *x, *ba, *bna, *bma, *bm, *bhm;
  const short *Wh[13], *Wl[13];   // 0 Wa,1 Ua,2 Wna,3 Una,4 WAt,5 UAt,6 VAt,7 Wma,8 Uma,9 Wm,10 Um,11 Whm,12 Uhm
  float *Hb0, *Hb1, *Hb2, *Nst, *zA, *NrA, *s1, *score, *mbuf, *zM, *mrM, *out;
  unsigned* cnt;
};

// ---------------------------------------------------------------------------
// Weight prepack: fp32 [K][N] -> fragment-major bf16 hi/lo.
// elem(lane,j) = W[kc*32 + (lane>>4)*8 + j][ntg*16 + (lane&15)] at
// offset ((kc*(N/16)+ntg)*64 + lane)*8 + j.  One 16B load/lane per B-fragment.
// ---------------------------------------------------------------------------
__global__ __launch_bounds__(256)
void prepack(const float* __restrict__ W, short* __restrict__ Whi,
             short* __restrict__ Wlo, int N)
{
  __shared__ float lds[32][257];
  const int tid = threadIdx.x;
  const int k0 = blockIdx.y * 32;
  const int n0 = blockIdx.x * 256;
  #pragma unroll
  for (int i = 0; i < 8; ++i) {
    const int flat = (i * 256 + tid) * 4;
    const int r = flat >> 8, c = flat & 255;
    const float4 v = *(const float4*)(W + (size_t)(k0 + r) * N + n0 + c);
    lds[r][c] = v.x; lds[r][c + 1] = v.y; lds[r][c + 2] = v.z; lds[r][c + 3] = v.w;
  }
  __syncthreads();
  const int lane = tid & 63, wv = tid >> 6;
  const int kr = (lane >> 4) * 8;
  const int cc = lane & 15;
  for (int nt = wv; nt < 16; nt += 4) {
    const int ntg = (n0 >> 4) + nt;
    const size_t off = ((size_t)((k0 >> 5) * (N >> 4) + ntg) * 64 + lane) * 8;
    bf16x8 vh, vl;
    #pragma unroll
    for (int j = 0; j < 8; ++j) {
      const float v = lds[kr + j][nt * 16 + cc];
      const short hb = f2bf(v);
      vh[j] = hb; vl[j] = f2bf(v - bf2f(hb));
    }
    *(bf16x8*)(Whi + off) = vh;
    *(bf16x8*)(Wlo + off) = vl;
  }
}

// ---------------------------------------------------------------------------
// LDS A-operand staging: 16 rows x K fp32 -> fragment-major hi/lo bf16.
// Dest short index: ((kc*64 + dl)*8 + j), dl = r | ((sub>>3)<<4), sub=k&31.
// ---------------------------------------------------------------------------
__device__ __forceinline__ void store4(float4 v, int r, int k0, short* hi, short* lo) {
  const int sub = k0 & 31;
  const int o = ((((k0 >> 5) << 6) | r | ((sub >> 3) << 4)) << 3) | (sub & 7);
  const short h0 = f2bf(v.x), h1 = f2bf(v.y), h2 = f2bf(v.z), h3 = f2bf(v.w);
  *(u64*)(hi + o) = pk(h0, h1, h2, h3);
  *(u64*)(lo + o) = pk(f2bf(v.x - bf2f(h0)), f2bf(v.y - bf2f(h1)),
                       f2bf(v.z - bf2f(h2)), f2bf(v.w - bf2f(h3)));
}

template<int LOGK>
__device__ __forceinline__ void stageA(const float* __restrict__ src, int ld,
                                       short* hi, short* lo, int tid) {
  constexpr int K = 1 << LOGK;
  constexpr int NF4 = K * 4;               // (16*K)/4 float4s
  #pragma unroll
  for (int it = 0; it < (NF4 + NTHR - 1) / NTHR; ++it) {
    const int f4 = it * NTHR + tid;
    if (NF4 % NTHR == 0 || f4 < NF4) {
      const int f = f4 << 2, r = f >> LOGK, k0 = f & (K - 1);
      store4(*(const float4*)(src + r * ld + k0), r, k0, hi, lo);
    }
  }
}

template<int LOGK>
__device__ __forceinline__ void stageAdiff(const float* __restrict__ a,
                                           const float* __restrict__ b, int ld,
                                           short* hi, short* lo, int tid) {
  constexpr int K = 1 << LOGK;
  constexpr int NF4 = K * 4;
  #pragma unroll
  for (int it = 0; it < (NF4 + NTHR - 1) / NTHR; ++it) {
    const int f4 = it * NTHR + tid;
    if (NF4 % NTHR == 0 || f4 < NF4) {
      const int f = f4 << 2, r = f >> LOGK, k0 = f & (K - 1);
      const float4 u = *(const float4*)(a + r * ld + k0);
      const float4 w = *(const float4*)(b + r * ld + k0);
      store4((float4){u.x - w.x, u.y - w.y, u.z - w.z, u.w - w.w}, r, k0, hi, lo);
    }
  }
}

// MFMA over kc range: acc += A(lds)@W(packed), 3-term hi/lo split (~fp24).
__device__ __forceinline__ void mm(const short* Ah, const short* Al,
                                   const short* __restrict__ Wh,
                                   const short* __restrict__ Wl,
                                   int ntN, int ntg, int kc0, int kc1,
                                   int lane, f32x4& acc)
{
  for (int kc = kc0; kc < kc1; ++kc) {
    const bf16x8 ah = *(const bf16x8*)(Ah + (((kc << 6) | lane) << 3));
    const bf16x8 al = *(const bf16x8*)(Al + (((kc << 6) | lane) << 3));
    const size_t o = ((size_t)((kc * ntN + ntg) << 6 | lane)) << 3;
    const bf16x8 bh = *(const bf16x8*)(Wh + o);
    const bf16x8 bl = *(const bf16x8*)(Wl + o);
    acc = __builtin_amdgcn_mfma_f32_16x16x32_bf16(ah, bh, acc, 0, 0, 0);
    acc = __builtin_amdgcn_mfma_f32_16x16x32_bf16(al, bh, acc, 0, 0, 0);
    acc = __builtin_amdgcn_mfma_f32_16x16x32_bf16(ah, bl, acc, 0, 0, 0);
  }
}

// Device-wide barrier: 8 spread counters, release-add / relaxed-poll / acquire.
__device__ __forceinline__ void gbar(unsigned* cnt, int bid, unsigned& ph) {
  __syncthreads();
  ++ph;
  if (threadIdx.x == 0) {
    __hip_atomic_fetch_add(&cnt[(bid & 7) << 5], 1u, __ATOMIC_RELEASE,
                           __HIP_MEMORY_SCOPE_AGENT);
    const unsigned tgt = ph * (unsigned)NBLK;
    for (;;) {
      unsigned s = 0;
      #pragma unroll
      for (int i = 0; i < 8; ++i)
        s += __hip_atomic_load(&cnt[i << 5], __ATOMIC_RELAXED,
                               __HIP_MEMORY_SCOPE_AGENT);
      if (s >= tgt) break;
      __builtin_amdgcn_s_sleep(2);
    }
    __builtin_amdgcn_fence(__ATOMIC_ACQUIRE, "agent");
  }
  __syncthreads();
}

// ---------------------------------------------------------------------------
// Persistent kernel: 256 blocks = 16 row-stripes x 16 colgroups; 8 waves each.
// All 256 timesteps; 7 device barriers per step.
// ---------------------------------------------------------------------------
__global__ __launch_bounds__(NTHR, 1)
void dtgru(KP P)
{
  __shared__ short sAh[8192], sAl[8192];   // slotA: 16 x 512 (fragment-major)
  __shared__ short sBh[8192], sBl[8192];   // slotB
  __shared__ short sXh[1024], sXl[1024];   // x slot: 16 x 64
  __shared__ float red[1536];              // cross-wave reduction
  const int tid = threadIdx.x, lane = tid & 63, wid = tid >> 6;
  const int bid = blockIdx.x;
  const int g = bid & 15;                  // colgroup (low bits -> XCD-local weights)
  const int r0 = (bid >> 4) << 4;          // stripe rows [r0, r0+16)
  unsigned ph = 0;
  float* Hb[3] = {P.Hb0, P.Hb1, P.Hb2};

  #pragma clang loop unroll(disable)
  for (int t = 0; t < Tseq; ++t) {
    float* Hcur = Hb[t % 3];
    float* Hm1  = Hb[(t + 2) % 3];
    float* Hm2  = Hb[(t + 1) % 3];

    // ---- P1: gates_A = dt@Wa + N@Ua + ba -> zA, NrA ----------------------
    stageAdiff<9>(Hm1 + (r0 << 9), Hm2 + (r0 << 9), 512, sAh, sAl, tid);
    stageA<9>(P.Nst + (r0 << 9), 512, sBh, sBl, tid);
    __syncthreads();
    {
      f32x4 acc = {0.f, 0.f, 0.f, 0.f};
      const int nt = wid & 3, half = wid >> 2, ntg = (g << 2) | nt;
      if (!half) mm(sAh, sAl, P.Wh[0], P.Wl[0], 64, ntg, 0, 16, lane, acc);
      else       mm(sBh, sBl, P.Wh[1], P.Wl[1], 64, ntg, 0, 16, lane, acc);
      if (half) *(f32x4*)&red[(nt << 8) | (lane << 2)] = acc;
      __syncthreads();
      if (!half) {
        acc += *(f32x4*)&red[(nt << 8) | (lane << 2)];
        const int col = (g << 6) | (nt << 4) | (lane & 15);
        const float b = P.ba[col];
        const int rb = r0 + ((lane >> 4) << 2);
        #pragma unroll
        for (int i = 0; i < 4; ++i) {
          const int row = rb + i;
          const float sg = sigm(acc[i] + b);
          if (col < 512) P.zA[(row << 9) | col] = sg;
          else { const int j = col - 512; P.NrA[(row << 9) | j] = P.Nst[(row << 9) | j] * sg; }
        }
      }
    }
    gbar(P.cnt, bid, ph);

    // ---- P2: N_new = (1-zA)N + zA tanh(dt@Wna + NrA@Una + bna) -----------
    stageA<9>(P.NrA + (r0 << 9), 512, sBh, sBl, tid);   // slotA keeps dt
    __syncthreads();
    {
      f32x4 acc = {0.f, 0.f, 0.f, 0.f};
      const int nt = wid & 1, q = wid >> 1, ntg = (g << 1) | nt;
      const int kc0 = (q & 1) << 3;
      if (!(q >> 1)) mm(sAh, sAl, P.Wh[2], P.Wl[2], 32, ntg, kc0, kc0 + 8, lane, acc);
      else           mm(sBh, sBl, P.Wh[3], P.Wl[3], 32, ntg, kc0, kc0 + 8, lane, acc);
      if (q) *(f32x4*)&red[((((q - 1) << 1) | nt) << 8) | (lane << 2)] = acc;
      __syncthreads();
      if (!q) {
        #pragma unroll
        for (int j = 0; j < 3; ++j) acc += *(f32x4*)&red[(((j << 1) | nt) << 8) | (lane << 2)];
        const int col = (g << 5) | (nt << 4) | (lane & 15);
        const float b = P.bna[col];
        const int rb = r0 + ((lane >> 4) << 2);
        #pragma unroll
        for (int i = 0; i < 4; ++i) {
          const int idx = ((rb + i) << 9) | col;
          const float hn = tanhf(acc[i] + b);
          const float z = P.zA[idx];
          P.Nst[idx] = (1.f - z) * P.Nst[idx] + z * hn;
        }
      }
    }
    gbar(P.cnt, bid, ph);

    // ---- P3: s1 = tanh(h@WAttn + N_new@UAttn) ----------------------------
    stageA<9>(Hm1 + (r0 << 9), 512, sAh, sAl, tid);
    stageA<9>(P.Nst + (r0 << 9), 512, sBh, sBl, tid);
    __syncthreads();
    {
      f32x4 acc = {0.f, 0.f, 0.f, 0.f};
      const int nt = wid & 1, q = wid >> 1, ntg = (g << 1) | nt;
      const int kc0 = (q & 1) << 3;
      if (!(q >> 1)) mm(sAh, sAl, P.Wh[4], P.Wl[4], 32, ntg, kc0, kc0 + 8, lane, acc);
      else           mm(sBh, sBl, P.Wh[5], P.Wl[5], 32, ntg, kc0, kc0 + 8, lane, acc);
      if (q) *(f32x4*)&red[((((q - 1) << 1) | nt) << 8) | (lane << 2)] = acc;
      __syncthreads();
      if (!q) {
        #pragma unroll
        for (int j = 0; j < 3; ++j) acc += *(f32x4*)&red[(((j << 1) | nt) << 8) | (lane << 2)];
        const int col = (g << 5) | (nt << 4) | (lane & 15);
        const int rb = r0 + ((lane >> 4) << 2);
        #pragma unroll
        for (int i = 0; i < 4; ++i) P.s1[((rb + i) << 9) | col] = tanhf(acc[i]);
      }
    }
    gbar(P.cnt, bid, ph);

    // ---- P4: score = s1@VAttn  (slotA keeps h) ---------------------------
    stageA<9>(P.s1 + (r0 << 9), 512, sBh, sBl, tid);
    __syncthreads();
    {
      f32x4 acc = {0.f, 0.f, 0.f, 0.f};
      const int nt = wid & 1, q = wid >> 1, ntg = (g << 1) | nt;
      mm(sBh, sBl, P.Wh[6], P.Wl[6], 32, ntg, q << 2, (q << 2) + 4, lane, acc);
      if (q) *(f32x4*)&red[((((q - 1) << 1) | nt) << 8) | (lane << 2)] = acc;
      __syncthreads();
      if (!q) {
        #pragma unroll
        for (int j = 0; j < 3; ++j) acc += *(f32x4*)&red[(((j << 1) | nt) << 8) | (lane << 2)];
        const int col = (g << 5) | (nt << 4) | (lane & 15);
        const int rb = r0 + ((lane >> 4) << 2);
        #pragma unroll
        for (int i = 0; i < 4; ++i) P.score[((rb + i) << 9) | col] = acc[i];
      }
    }
    gbar(P.cnt, bid, ph);

    // ---- P5: softmax+Omega (in-block) ; m = tanh(Omega@Wma + h@Uma + bma)
    {
      #pragma unroll
      for (int rr = 0; rr < 2; ++rr) {
        const int row = r0 + (wid << 1) + rr;
        const float* sr = P.score + (row << 9);
        const int k0 = lane << 3;
        const float4 v0 = *(const float4*)(sr + k0);
        const float4 v1 = *(const float4*)(sr + k0 + 4);
        float mx = fmaxf(fmaxf(fmaxf(v0.x, v0.y), fmaxf(v0.z, v0.w)),
                         fmaxf(fmaxf(v1.x, v1.y), fmaxf(v1.z, v1.w)));
        #pragma unroll
        for (int d = 1; d < 64; d <<= 1) mx = fmaxf(mx, __shfl_xor(mx, d));
        float e[8] = {expf(v0.x - mx), expf(v0.y - mx), expf(v0.z - mx), expf(v0.w - mx),
                      expf(v1.x - mx), expf(v1.y - mx), expf(v1.z - mx), expf(v1.w - mx)};
        float sm = ((e[0] + e[1]) + (e[2] + e[3])) + ((e[4] + e[5]) + (e[6] + e[7]));
        #pragma unroll
        for (int d = 1; d < 64; d <<= 1) sm += __shfl_xor(sm, d);
        const float inv = 1.f / sm;
        const float* nr = P.Nst + (row << 9);
        const float4 n0 = *(const float4*)(nr + k0);
        const float4 n1 = *(const float4*)(nr + k0 + 4);
        const float om[8] = {e[0] * inv * n0.x, e[1] * inv * n0.y, e[2] * inv * n0.z, e[3] * inv * n0.w,
                             e[4] * inv * n1.x, e[5] * inv * n1.y, e[6] * inv * n1.z, e[7] * inv * n1.w};
        short h[8], l[8];
        #pragma unroll
        for (int j = 0; j < 8; ++j) { h[j] = f2bf(om[j]); l[j] = f2bf(om[j] - bf2f(h[j])); }
        const int o = (((lane >> 2) << 6) | (row & 15) | ((lane & 3) << 4)) << 3;
        *(u64*)(sBh + o)     = pk(h[0], h[1], h[2], h[3]);
        *(u64*)(sBh + o + 4) = pk(h[4], h[5], h[6], h[7]);
        *(u64*)(sBl + o)     = pk(l[0], l[1], l[2], l[3]);
        *(u64*)(sBl + o + 4) = pk(l[4], l[5], l[6], l[7]);
      }
      __syncthreads();
      f32x4 acc = {0.f, 0.f, 0.f, 0.f};
      const int nt = wid & 1, q = wid >> 1, ntg = (g << 1) | nt;
      const int kc0 = (q & 1) << 3;
      if (!(q >> 1)) mm(sBh, sBl, P.Wh[7], P.Wl[7], 32, ntg, kc0, kc0 + 8, lane, acc);  // Omega@Wma
      else           mm(sAh, sAl, P.Wh[8], P.Wl[8], 32, ntg, kc0, kc0 + 8, lane, acc);  // h@Uma
      if (q) *(f32x4*)&red[((((q - 1) << 1) | nt) << 8) | (lane << 2)] = acc;
      __syncthreads();
      if (!q) {
        #pragma unroll
        for (int j = 0; j < 3; ++j) acc += *(f32x4*)&red[(((j << 1) | nt) << 8) | (lane << 2)];
        const int col = (g << 5) | (nt << 4) | (lane & 15);
        const float b = P.bma[col];
        const int rb = r0 + ((lane >> 4) << 2);
        #pragma unroll
        for (int i = 0; i < 4; ++i) P.mbuf[((rb + i) << 9) | col] = tanhf(acc[i] + b);
      }
    }
    gbar(P.cnt, bid, ph);

    // ---- P6: gates_M = x_t@Wm + m@Um + bm -> zM, mrM ---------------------
    stageA<6>(P.x + ((size_t)r0 * 256 + t) * 64, Tseq * Ein, sXh, sXl, tid);
    stageA<9>(P.mbuf + (r0 << 9), 512, sBh, sBl, tid);
    __syncthreads();
    {
      f32x4 acc = {0.f, 0.f, 0.f, 0.f};
      const int nt = wid & 3, half = wid >> 2, ntg = (g << 2) | nt;
      if (!half) {
        mm(sXh, sXl, P.Wh[9],  P.Wl[9],  64, ntg, 0, 2, lane, acc);
        mm(sBh, sBl, P.Wh[10], P.Wl[10], 64, ntg, 0, 7, lane, acc);
      } else {
        mm(sBh, sBl, P.Wh[10], P.Wl[10], 64, ntg, 7, 16, lane, acc);
      }
      if (half) *(f32x4*)&red[(nt << 8) | (lane << 2)] = acc;
      __syncthreads();
      if (!half) {
        acc += *(f32x4*)&red[(nt << 8) | (lane << 2)];
        const int col = (g << 6) | (nt << 4) | (lane & 15);
        const float b = P.bm[col];
        const int rb = r0 + ((lane >> 4) << 2);
        #pragma unroll
        for (int i = 0; i < 4; ++i) {
          const int row = rb + i;
          const float sg = sigm(acc[i] + b);
          if (col < 512) P.zM[(row << 9) | col] = sg;
          else { const int j = col - 512; P.mrM[(row << 9) | j] = P.mbuf[(row << 9) | j] * sg; }
        }
      }
    }
    gbar(P.cnt, bid, ph);

    // ---- P7: h_new = (1-zM)h + zM tanh(x@Whm + mrM@Uhm + bhm) ------------
    stageA<9>(P.mrM + (r0 << 9), 512, sBh, sBl, tid);
    __syncthreads();
    {
      f32x4 acc = {0.f, 0.f, 0.f, 0.f};
      const int nt = wid & 1, q = wid >> 1, ntg = (g << 1) | nt;
      if (q == 0) {
        mm(sXh, sXl, P.Wh[11], P.Wl[11], 32, ntg, 0, 2, lane, acc);
        mm(sBh, sBl, P.Wh[12], P.Wl[12], 32, ntg, 0, 2, lane, acc);
      } else if (q == 1) mm(sBh, sBl, P.Wh[12], P.Wl[12], 32, ntg, 2, 7, lane, acc);
      else if (q == 2)   mm(sBh, sBl, P.Wh[12], P.Wl[12], 32, ntg, 7, 12, lane, acc);
      else               mm(sBh, sBl, P.Wh[12], P.Wl[12], 32, ntg, 12, 16, lane, acc);
      if (q) *(f32x4*)&red[((((q - 1) << 1) | nt) << 8) | (lane << 2)] = acc;
      __syncthreads();
      if (!q) {
        #pragma unroll
        for (int j = 0; j < 3; ++j) acc += *(f32x4*)&red[(((j << 1) | nt) << 8) | (lane << 2)];
        const int col = (g << 5) | (nt << 4) | (lane & 15);
        const float b = P.bhm[col];
        const int rb = r0 + ((lane >> 4) << 2);
        #pragma unroll
        for (int i = 0; i < 4; ++i) {
          const int row = rb + i;
          const int idx = (row << 9) | col;
          const float hh = tanhf(acc[i] + b);
          const float z = P.zM[idx];
          const float hnew = (1.f - z) * Hm1[idx] + z * hh;
          Hcur[idx] = hnew;
          P.out[(((size_t)row << 8) | t) << 9 | col] = hnew;
        }
      }
    }
    gbar(P.cnt, bid, ph);
  }
}

__global__ __launch_bounds__(256)
void initk(float* h1, float* h2, float* n, unsigned* cnt) {
  const int i = blockIdx.x * 256 + threadIdx.x;
  h1[i] = 0.f; h2[i] = 0.f; n[i] = 0.f;
  if (blockIdx.x == 0) cnt[threadIdx.x] = 0u;
}

__global__ __launch_bounds__(256)
void finalize(const float* __restrict__ hT, const float* __restrict__ nT,
              float* __restrict__ oh, float* __restrict__ on) {
  const int i = blockIdx.x * 256 + threadIdx.x;
  oh[i] = hT[i]; on[i] = nT[i];
}

extern "C" void kernel_launch(void* const* d_in, const int* in_sizes, int n_in,
                              void* d_out, int out_size, void* d_ws, size_t ws_size,
                              hipStream_t stream)
{
  (void)in_sizes; (void)n_in; (void)out_size; (void)ws_size;

  unsigned* cnt = (unsigned*)d_ws;          // 256 u32 (8 used, cacheline-spread)
  float* w = (float*)d_ws + 256;
  const int S = Bsz * Hd;                   // 131072

  KP P{};
  P.x   = (const float*)d_in[0];
  P.ba  = (const float*)d_in[3];
  P.bna = (const float*)d_in[6];
  P.bma = (const float*)d_in[12];
  P.bm  = (const float*)d_in[15];
  P.bhm = (const float*)d_in[18];
  P.Hb0 = w;          P.Hb1 = w + S;      P.Hb2 = w + 2 * S;
  P.Nst = w + 3 * S;  P.zA  = w + 4 * S;  P.NrA = w + 5 * S;
  P.s1  = w + 6 * S;  P.score = w + 7 * S; P.mbuf = w + 8 * S;
  P.zM  = w + 9 * S;  P.mrM = w + 10 * S;
  P.out = (float*)d_out;
  P.cnt = cnt;
  float* out_hT = P.out + (size_t)Bsz * Tseq * Hd;
  float* out_NT = out_hT + S;

  // packed weights after fp32 scratch
  short* wpk = (short*)(w + 11 * S);
  const int widx[13] = {1, 2, 4, 5, 7, 8, 9, 10, 11, 13, 14, 16, 17};
  const int wK[13]   = {512, 512, 512, 512, 512, 512, 512, 512, 512, 64, 512, 64, 512};
  const int wN[13]   = {1024, 1024, 512, 512, 512, 512, 512, 512, 512, 1024, 1024, 512, 512};
  {
    size_t off = 0;
    for (int i = 0; i < 13; ++i) {
      const size_t sz = (size_t)wK[i] * wN[i];
      P.Wh[i] = wpk + off; off += sz;
      P.Wl[i] = wpk + off; off += sz;
    }
  }
  for (int i = 0; i < 13; ++i) {
    dim3 gg(wN[i] / 256, wK[i] / 32);
    prepack<<<gg, 256, 0, stream>>>((const float*)d_in[widx[i]],
                                    (short*)P.Wh[i], (short*)P.Wl[i], wN[i]);
  }

  initk<<<S / 256, 256, 0, stream>>>(P.Hb1, P.Hb2, P.Nst, cnt);

  dtgru<<<NBLK, NTHR, 0, stream>>>(P);

  finalize<<<S / 256, 256, 0, stream>>>(P.Hb0 /* (Tseq-1)%3 == 0 */, P.Nst,
                                        out_hT, out_NT);
}

// Round 6
// 20734.746 us; speedup vs baseline: 3.9032x; 1.6098x over previous
//
#include <hip/hip_runtime.h>

static constexpr int Bsz  = 256;   // batch
static constexpr int Tseq = 256;   // timesteps
static constexpr int Hd   = 512;   // d_model
static constexpr int Ein  = 64;    // enc_in
static constexpr int NBLK = 256;   // persistent blocks (1 per CU)
static constexpr int NTHR = 512;   // 8 waves per block

typedef __attribute__((ext_vector_type(8))) short bf16x8;
typedef __attribute__((ext_vector_type(4))) float f32x4;
typedef unsigned long long u64;

__device__ __forceinline__ float sigm(float x) { return 1.f / (1.f + expf(-x)); }
__device__ __forceinline__ short f2bf(float f) {   // RN-even fp32 -> bf16 bits
  union { float f; unsigned u; } v; v.f = f;
  unsigned r = v.u + 0x7FFFu + ((v.u >> 16) & 1u);
  return (short)(r >> 16);
}
__device__ __forceinline__ float bf2f(short s) {
  union { float f; unsigned u; } v; v.u = ((unsigned)(unsigned short)s) << 16; return v.f;
}

// ---- LLC-coherent (sc0 sc1) access: bypass L1/L2, serialize at LLC ----------
__device__ __forceinline__ void llc_ld4(f32x4& d, const float* p) {
  asm volatile("global_load_dwordx4 %0, %1, off sc0 sc1" : "=v"(d) : "v"(p));
}
__device__ __forceinline__ void llc_ld1(float& d, const float* p) {
  asm volatile("global_load_dword %0, %1, off sc0 sc1" : "=v"(d) : "v"(p));
}
__device__ __forceinline__ void llc_st1(float* p, float v) {
  asm volatile("global_store_dword %0, %1, off sc0 sc1" :: "v"(p), "v"(v) : "memory");
}
__device__ __forceinline__ void vwait() {           // complete all my VMEM ops
  asm volatile("s_waitcnt vmcnt(0)" ::: "memory");
  __builtin_amdgcn_sched_barrier(0);                // nothing crosses the wait
}

struct KP {
  const float *x, *ba, *bna, *bma, *bm, *bhm;
  const short *Wh[13], *Wl[13];   // 0 Wa,1 Ua,2 Wna,3 Una,4 WAt,5 UAt,6 VAt,7 Wma,8 Uma,9 Wm,10 Um,11 Whm,12 Uhm
  float *Hb0, *Hb1, *Hb2, *Nst, *zA, *NrA, *s1, *score, *mbuf, *zM, *mrM, *out;
  unsigned* cnt;
};

// ---------------------------------------------------------------------------
// Weight prepack: fp32 [K][N] -> fragment-major bf16 hi/lo.
// elem(lane,j) = W[kc*32 + (lane>>4)*8 + j][ntg*16 + (lane&15)] at
// offset ((kc*(N/16)+ntg)*64 + lane)*8 + j.  One 16B load/lane per B-fragment.
// ---------------------------------------------------------------------------
__global__ __launch_bounds__(256)
void prepack(const float* __restrict__ W, short* __restrict__ Whi,
             short* __restrict__ Wlo, int N)
{
  __shared__ float lds[32][257];
  const int tid = threadIdx.x;
  const int k0 = blockIdx.y * 32;
  const int n0 = blockIdx.x * 256;
  #pragma unroll
  for (int i = 0; i < 8; ++i) {
    const int flat = (i * 256 + tid) * 4;
    const int r = flat >> 8, c = flat & 255;
    const float4 v = *(const float4*)(W + (size_t)(k0 + r) * N + n0 + c);
    lds[r][c] = v.x; lds[r][c + 1] = v.y; lds[r][c + 2] = v.z; lds[r][c + 3] = v.w;
  }
  __syncthreads();
  const int lane = tid & 63, wv = tid >> 6;
  const int kr = (lane >> 4) * 8;
  const int cc = lane & 15;
  for (int nt = wv; nt < 16; nt += 4) {
    const int ntg = (n0 >> 4) + nt;
    const size_t off = ((size_t)((k0 >> 5) * (N >> 4) + ntg) * 64 + lane) * 8;
    bf16x8 vh, vl;
    #pragma unroll
    for (int j = 0; j < 8; ++j) {
      const float v = lds[kr + j][nt * 16 + cc];
      const short hb = f2bf(v);
      vh[j] = hb; vl[j] = f2bf(v - bf2f(hb));
    }
    *(bf16x8*)(Whi + off) = vh;
    *(bf16x8*)(Wlo + off) = vl;
  }
}

// ---------------------------------------------------------------------------
// Staging task map (conflict-free LDS): task = (kc<<6)|dl, dl = lane pattern.
// Thread owns task(s); reads A[dl&15][kc*32 + (dl>>4)*8 .. +7] (2 x float4 sc),
// writes hi/lo bf16x8 at short-offset task<<3 -> per-wave lane-linear 16B
// stride ds_write_b128 (canonical conflict-free).
// ---------------------------------------------------------------------------
__device__ __forceinline__ const float* task_ptr(const float* src, int ld, int task) {
  const int kc = task >> 6, dl = task & 63;
  return src + (dl & 15) * ld + kc * 32 + ((dl >> 4) << 3);
}
__device__ __forceinline__ void stage_issue(const float* src, int ld, int task,
                                            f32x4& u0, f32x4& u1) {
  const float* p = task_ptr(src, ld, task);
  llc_ld4(u0, p); llc_ld4(u1, p + 4);
}
__device__ __forceinline__ void task_write(int task, f32x4 u0, f32x4 u1,
                                           short* hi, short* lo) {
  const int o = task << 3;
  bf16x8 vh, vl;
  #pragma unroll
  for (int j = 0; j < 4; ++j) {
    const short h0 = f2bf(u0[j]); vh[j]     = h0; vl[j]     = f2bf(u0[j] - bf2f(h0));
    const short h1 = f2bf(u1[j]); vh[j + 4] = h1; vl[j + 4] = f2bf(u1[j] - bf2f(h1));
  }
  *(bf16x8*)(hi + o) = vh;
  *(bf16x8*)(lo + o) = vl;
}

// MFMA over kc range: acc += A(lds)@W(packed), 3-term hi/lo split (~fp24).
// Weights via NORMAL cached loads (stay L2-resident; never invalidated).
__device__ __forceinline__ void mm(const short* Ah, const short* Al,
                                   const short* __restrict__ Wh,
                                   const short* __restrict__ Wl,
                                   int ntN, int ntg, int kc0, int kc1,
                                   int lane, f32x4& acc)
{
  for (int kc = kc0; kc < kc1; ++kc) {
    const bf16x8 ah = *(const bf16x8*)(Ah + (((kc << 6) | lane) << 3));
    const bf16x8 al = *(const bf16x8*)(Al + (((kc << 6) | lane) << 3));
    const size_t o = ((size_t)((kc * ntN + ntg) << 6 | lane)) << 3;
    const bf16x8 bh = *(const bf16x8*)(Wh + o);
    const bf16x8 bl = *(const bf16x8*)(Wl + o);
    acc = __builtin_amdgcn_mfma_f32_16x16x32_bf16(ah, bh, acc, 0, 0, 0);
    acc = __builtin_amdgcn_mfma_f32_16x16x32_bf16(al, bh, acc, 0, 0, 0);
    acc = __builtin_amdgcn_mfma_f32_16x16x32_bf16(ah, bl, acc, 0, 0, 0);
  }
}

// Per-stripe barrier: 16 blocks/stripe, relaxed agent atomics at LLC.
// No cache fences needed: all cross-block state uses sc0/sc1 (LLC-coherent);
// vmcnt(0) before __syncthreads guarantees stores are LLC-visible pre-signal.
__device__ __forceinline__ void gbar(unsigned* cnt, int stripe, unsigned& ph) {
  asm volatile("s_waitcnt vmcnt(0)" ::: "memory");
  __syncthreads();
  ++ph;
  if (threadIdx.x == 0) {
    __hip_atomic_fetch_add(&cnt[stripe << 4], 1u, __ATOMIC_RELAXED,
                           __HIP_MEMORY_SCOPE_AGENT);
    const unsigned tgt = ph * 16u;
    while (__hip_atomic_load(&cnt[stripe << 4], __ATOMIC_RELAXED,
                             __HIP_MEMORY_SCOPE_AGENT) < tgt)
      __builtin_amdgcn_s_sleep(1);
  }
  __syncthreads();
}

// ---------------------------------------------------------------------------
// Persistent kernel: 256 blocks = 16 row-stripes x 16 colgroups; 8 waves each.
// All 256 timesteps; 7 per-stripe barriers per step.
// ---------------------------------------------------------------------------
__global__ __launch_bounds__(NTHR, 1)
void dtgru(KP P)
{
  __shared__ short sAh[8192], sAl[8192];   // slotA: 16 x 512 (fragment-major)
  __shared__ short sBh[8192], sBl[8192];   // slotB
  __shared__ short sXh[1024], sXl[1024];   // x slot: 16 x 64
  __shared__ float red[1536];              // cross-wave reduction
  const int tid = threadIdx.x, lane = tid & 63, wid = tid >> 6;
  const int bid = blockIdx.x;
  const int g = bid & 15;                  // colgroup (bid&7 -> XCD: weights L2-local)
  const int stripe = bid >> 4;
  const int r0 = stripe << 4;              // rows [r0, r0+16)
  unsigned ph = 0;
  float* Hb[3] = {P.Hb0, P.Hb1, P.Hb2};
  float* const Nstr = P.Nst + (r0 << 9);

  #pragma clang loop unroll(disable)
  for (int t = 0; t < Tseq; ++t) {
    float* Hcur = Hb[t % 3];
    float* Hm1  = Hb[(t + 2) % 3];
    float* Hm2  = Hb[(t + 1) % 3];
    const float* Hm1r = Hm1 + (r0 << 9);
    const float* Hm2r = Hm2 + (r0 << 9);

    // ---- P1: gates_A = dt@Wa + N@Ua + ba -> zA, NrA ----------------------
    {
      f32x4 a0,a1,a2,a3, b0,b1,b2,b3, n0,n1,n2,n3;
      stage_issue(Hm1r, 512, tid,       a0, a1);
      stage_issue(Hm2r, 512, tid,       b0, b1);
      stage_issue(Hm1r, 512, tid + 512, a2, a3);
      stage_issue(Hm2r, 512, tid + 512, b2, b3);
      stage_issue(Nstr, 512, tid,       n0, n1);
      stage_issue(Nstr, 512, tid + 512, n2, n3);
      vwait();
      task_write(tid,       a0 - b0, a1 - b1, sAh, sAl);
      task_write(tid + 512, a2 - b2, a3 - b3, sAh, sAl);
      task_write(tid,       n0, n1, sBh, sBl);
      task_write(tid + 512, n2, n3, sBh, sBl);
    }
    __syncthreads();
    {
      f32x4 acc = {0.f, 0.f, 0.f, 0.f};
      const int nt = wid & 3, half = wid >> 2, ntg = (g << 2) | nt;
      if (!half) mm(sAh, sAl, P.Wh[0], P.Wl[0], 64, ntg, 0, 16, lane, acc);
      else       mm(sBh, sBl, P.Wh[1], P.Wl[1], 64, ntg, 0, 16, lane, acc);
      if (half) *(f32x4*)&red[(nt << 8) | (lane << 2)] = acc;
      __syncthreads();
      if (!half) {
        acc += *(f32x4*)&red[(nt << 8) | (lane << 2)];
        const int col = (g << 6) | (nt << 4) | (lane & 15);
        const float b = P.ba[col];
        const int rb = r0 + ((lane >> 4) << 2);
        if (col < 512) {
          #pragma unroll
          for (int i = 0; i < 4; ++i)
            llc_st1(&P.zA[((rb + i) << 9) | col], sigm(acc[i] + b));
        } else {
          const int j = col - 512;
          float nv[4];
          #pragma unroll
          for (int i = 0; i < 4; ++i) llc_ld1(nv[i], &P.Nst[((rb + i) << 9) | j]);
          vwait();
          #pragma unroll
          for (int i = 0; i < 4; ++i)
            llc_st1(&P.NrA[((rb + i) << 9) | j], nv[i] * sigm(acc[i] + b));
        }
      }
    }
    gbar(P.cnt, stripe, ph);

    // ---- P2: N_new = (1-zA)N + zA tanh(dt@Wna + NrA@Una + bna) -----------
    {
      f32x4 m0,m1,m2,m3;
      stage_issue(P.NrA + (r0 << 9), 512, tid,       m0, m1);
      stage_issue(P.NrA + (r0 << 9), 512, tid + 512, m2, m3);
      vwait();
      task_write(tid,       m0, m1, sBh, sBl);   // slotA keeps dt
      task_write(tid + 512, m2, m3, sBh, sBl);
    }
    __syncthreads();
    {
      f32x4 acc = {0.f, 0.f, 0.f, 0.f};
      const int nt = wid & 1, q = wid >> 1, ntg = (g << 1) | nt;
      const int kc0 = (q & 1) << 3;
      if (!(q >> 1)) mm(sAh, sAl, P.Wh[2], P.Wl[2], 32, ntg, kc0, kc0 + 8, lane, acc);
      else           mm(sBh, sBl, P.Wh[3], P.Wl[3], 32, ntg, kc0, kc0 + 8, lane, acc);
      if (q) *(f32x4*)&red[((((q - 1) << 1) | nt) << 8) | (lane << 2)] = acc;
      __syncthreads();
      if (!q) {
        #pragma unroll
        for (int j = 0; j < 3; ++j) acc += *(f32x4*)&red[(((j << 1) | nt) << 8) | (lane << 2)];
        const int col = (g << 5) | (nt << 4) | (lane & 15);
        const float b = P.bna[col];
        const int rb = r0 + ((lane >> 4) << 2);
        float zv[4], nv[4];
        #pragma unroll
        for (int i = 0; i < 4; ++i) {
          const int idx = ((rb + i) << 9) | col;
          llc_ld1(zv[i], &P.zA[idx]); llc_ld1(nv[i], &P.Nst[idx]);
        }
        vwait();
        #pragma unroll
        for (int i = 0; i < 4; ++i) {
          const int idx = ((rb + i) << 9) | col;
          const float hn = tanhf(acc[i] + b);
          llc_st1(&P.Nst[idx], (1.f - zv[i]) * nv[i] + zv[i] * hn);
        }
      }
    }
    gbar(P.cnt, stripe, ph);

    // ---- P3: s1 = tanh(h@WAttn + N_new@UAttn) ----------------------------
    {
      f32x4 a0,a1,a2,a3, n0,n1,n2,n3;
      stage_issue(Hm1r, 512, tid,       a0, a1);
      stage_issue(Hm1r, 512, tid + 512, a2, a3);
      stage_issue(Nstr, 512, tid,       n0, n1);
      stage_issue(Nstr, 512, tid + 512, n2, n3);
      vwait();
      task_write(tid,       a0, a1, sAh, sAl);
      task_write(tid + 512, a2, a3, sAh, sAl);
      task_write(tid,       n0, n1, sBh, sBl);
      task_write(tid + 512, n2, n3, sBh, sBl);
    }
    __syncthreads();
    {
      f32x4 acc = {0.f, 0.f, 0.f, 0.f};
      const int nt = wid & 1, q = wid >> 1, ntg = (g << 1) | nt;
      const int kc0 = (q & 1) << 3;
      if (!(q >> 1)) mm(sAh, sAl, P.Wh[4], P.Wl[4], 32, ntg, kc0, kc0 + 8, lane, acc);
      else           mm(sBh, sBl, P.Wh[5], P.Wl[5], 32, ntg, kc0, kc0 + 8, lane, acc);
      if (q) *(f32x4*)&red[((((q - 1) << 1) | nt) << 8) | (lane << 2)] = acc;
      __syncthreads();
      if (!q) {
        #pragma unroll
        for (int j = 0; j < 3; ++j) acc += *(f32x4*)&red[(((j << 1) | nt) << 8) | (lane << 2)];
        const int col = (g << 5) | (nt << 4) | (lane & 15);
        const int rb = r0 + ((lane >> 4) << 2);
        #pragma unroll
        for (int i = 0; i < 4; ++i)
          llc_st1(&P.s1[((rb + i) << 9) | col], tanhf(acc[i]));
      }
    }
    gbar(P.cnt, stripe, ph);

    // ---- P4: score = s1@VAttn  (slotA keeps h) ---------------------------
    {
      f32x4 m0,m1,m2,m3;
      stage_issue(P.s1 + (r0 << 9), 512, tid,       m0, m1);
      stage_issue(P.s1 + (r0 << 9), 512, tid + 512, m2, m3);
      vwait();
      task_write(tid,       m0, m1, sBh, sBl);
      task_write(tid + 512, m2, m3, sBh, sBl);
    }
    __syncthreads();
    {
      f32x4 acc = {0.f, 0.f, 0.f, 0.f};
      const int nt = wid & 1, q = wid >> 1, ntg = (g << 1) | nt;
      mm(sBh, sBl, P.Wh[6], P.Wl[6], 32, ntg, q << 2, (q << 2) + 4, lane, acc);
      if (q) *(f32x4*)&red[((((q - 1) << 1) | nt) << 8) | (lane << 2)] = acc;
      __syncthreads();
      if (!q) {
        #pragma unroll
        for (int j = 0; j < 3; ++j) acc += *(f32x4*)&red[(((j << 1) | nt) << 8) | (lane << 2)];
        const int col = (g << 5) | (nt << 4) | (lane & 15);
        const int rb = r0 + ((lane >> 4) << 2);
        #pragma unroll
        for (int i = 0; i < 4; ++i)
          llc_st1(&P.score[((rb + i) << 9) | col], acc[i]);
      }
    }
    gbar(P.cnt, stripe, ph);

    // ---- P5: softmax+Omega (in-block) ; m = tanh(Omega@Wma + h@Uma + bma)
    {
      #pragma unroll
      for (int rr = 0; rr < 2; ++rr) {
        const int row = r0 + (wid << 1) + rr;
        const float* sr = P.score + (row << 9);
        const float* nr = P.Nst + (row << 9);
        const int k0 = lane << 3;
        f32x4 v0, v1, n0, n1;
        llc_ld4(v0, sr + k0); llc_ld4(v1, sr + k0 + 4);
        llc_ld4(n0, nr + k0); llc_ld4(n1, nr + k0 + 4);
        vwait();
        float mx = v0[0];
        #pragma unroll
        for (int j = 1; j < 4; ++j) mx = fmaxf(mx, v0[j]);
        #pragma unroll
        for (int j = 0; j < 4; ++j) mx = fmaxf(mx, v1[j]);
        #pragma unroll
        for (int d = 1; d < 64; d <<= 1) mx = fmaxf(mx, __shfl_xor(mx, d));
        float e[8];
        #pragma unroll
        for (int j = 0; j < 4; ++j) { e[j] = expf(v0[j] - mx); e[j + 4] = expf(v1[j] - mx); }
        float sm = ((e[0] + e[1]) + (e[2] + e[3])) + ((e[4] + e[5]) + (e[6] + e[7]));
        #pragma unroll
        for (int d = 1; d < 64; d <<= 1) sm += __shfl_xor(sm, d);
        const float inv = 1.f / sm;
        float om[8];
        #pragma unroll
        for (int j = 0; j < 4; ++j) { om[j] = e[j] * inv * n0[j]; om[j + 4] = e[j + 4] * inv * n1[j]; }
        short h[8], l[8];
        #pragma unroll
        for (int j = 0; j < 8; ++j) { h[j] = f2bf(om[j]); l[j] = f2bf(om[j] - bf2f(h[j])); }
        const int o = (((lane >> 2) << 6) | (row & 15) | ((lane & 3) << 4)) << 3;
        u64 ph0 = (u64)(unsigned short)h[0] | ((u64)(unsigned short)h[1] << 16)
                | ((u64)(unsigned short)h[2] << 32) | ((u64)(unsigned short)h[3] << 48);
        u64 ph1 = (u64)(unsigned short)h[4] | ((u64)(unsigned short)h[5] << 16)
                | ((u64)(unsigned short)h[6] << 32) | ((u64)(unsigned short)h[7] << 48);
        u64 pl0 = (u64)(unsigned short)l[0] | ((u64)(unsigned short)l[1] << 16)
                | ((u64)(unsigned short)l[2] << 32) | ((u64)(unsigned short)l[3] << 48);
        u64 pl1 = (u64)(unsigned short)l[4] | ((u64)(unsigned short)l[5] << 16)
                | ((u64)(unsigned short)l[6] << 32) | ((u64)(unsigned short)l[7] << 48);
        *(u64*)(sBh + o)     = ph0;
        *(u64*)(sBh + o + 4) = ph1;
        *(u64*)(sBl + o)     = pl0;
        *(u64*)(sBl + o + 4) = pl1;
      }
      __syncthreads();
      f32x4 acc = {0.f, 0.f, 0.f, 0.f};
      const int nt = wid & 1, q = wid >> 1, ntg = (g << 1) | nt;
      const int kc0 = (q & 1) << 3;
      if (!(q >> 1)) mm(sBh, sBl, P.Wh[7], P.Wl[7], 32, ntg, kc0, kc0 + 8, lane, acc);  // Omega@Wma
      else           mm(sAh, sAl, P.Wh[8], P.Wl[8], 32, ntg, kc0, kc0 + 8, lane, acc);  // h@Uma
      if (q) *(f32x4*)&red[((((q - 1) << 1) | nt) << 8) | (lane << 2)] = acc;
      __syncthreads();
      if (!q) {
        #pragma unroll
        for (int j = 0; j < 3; ++j) acc += *(f32x4*)&red[(((j << 1) | nt) << 8) | (lane << 2)];
        const int col = (g << 5) | (nt << 4) | (lane & 15);
        const float b = P.bma[col];
        const int rb = r0 + ((lane >> 4) << 2);
        #pragma unroll
        for (int i = 0; i < 4; ++i)
          llc_st1(&P.mbuf[((rb + i) << 9) | col], tanhf(acc[i] + b));
      }
    }
    gbar(P.cnt, stripe, ph);

    // ---- P6: gates_M = x_t@Wm + m@Um + bm -> zM, mrM ---------------------
    {
      f32x4 x0 = {0,0,0,0}, x1 = {0,0,0,0}, m0,m1,m2,m3;
      if (tid < 128)
        stage_issue(P.x + ((size_t)r0 * 256 + t) * 64, Tseq * Ein, tid, x0, x1);
      stage_issue(P.mbuf + (r0 << 9), 512, tid,       m0, m1);
      stage_issue(P.mbuf + (r0 << 9), 512, tid + 512, m2, m3);
      vwait();
      if (tid < 128) task_write(tid, x0, x1, sXh, sXl);
      task_write(tid,       m0, m1, sBh, sBl);
      task_write(tid + 512, m2, m3, sBh, sBl);
    }
    __syncthreads();
    {
      f32x4 acc = {0.f, 0.f, 0.f, 0.f};
      const int nt = wid & 3, half = wid >> 2, ntg = (g << 2) | nt;
      if (!half) {
        mm(sXh, sXl, P.Wh[9],  P.Wl[9],  64, ntg, 0, 2, lane, acc);
        mm(sBh, sBl, P.Wh[10], P.Wl[10], 64, ntg, 0, 7, lane, acc);
      } else {
        mm(sBh, sBl, P.Wh[10], P.Wl[10], 64, ntg, 7, 16, lane, acc);
      }
      if (half) *(f32x4*)&red[(nt << 8) | (lane << 2)] = acc;
      __syncthreads();
      if (!half) {
        acc += *(f32x4*)&red[(nt << 8) | (lane << 2)];
        const int col = (g << 6) | (nt << 4) | (lane & 15);
        const float b = P.bm[col];
        const int rb = r0 + ((lane >> 4) << 2);
        if (col < 512) {
          #pragma unroll
          for (int i = 0; i < 4; ++i)
            llc_st1(&P.zM[((rb + i) << 9) | col], sigm(acc[i] + b));
        } else {
          const int j = col - 512;
          float mv[4];
          #pragma unroll
          for (int i = 0; i < 4; ++i) llc_ld1(mv[i], &P.mbuf[((rb + i) << 9) | j]);
          vwait();
          #pragma unroll
          for (int i = 0; i < 4; ++i)
            llc_st1(&P.mrM[((rb + i) << 9) | j], mv[i] * sigm(acc[i] + b));
        }
      }
    }
    gbar(P.cnt, stripe, ph);

    // ---- P7: h_new = (1-zM)h + zM tanh(x@Whm + mrM@Uhm + bhm) ------------
    {
      f32x4 m0,m1,m2,m3;
      stage_issue(P.mrM + (r0 << 9), 512, tid,       m0, m1);
      stage_issue(P.mrM + (r0 << 9), 512, tid + 512, m2, m3);
      vwait();
      task_write(tid,       m0, m1, sBh, sBl);   // sX keeps x
      task_write(tid + 512, m2, m3, sBh, sBl);
    }
    __syncthreads();
    {
      f32x4 acc = {0.f, 0.f, 0.f, 0.f};
      const int nt = wid & 1, q = wid >> 1, ntg = (g << 1) | nt;
      if (q == 0) {
        mm(sXh, sXl, P.Wh[11], P.Wl[11], 32, ntg, 0, 2, lane, acc);
        mm(sBh, sBl, P.Wh[12], P.Wl[12], 32, ntg, 0, 2, lane, acc);
      } else if (q == 1) mm(sBh, sBl, P.Wh[12], P.Wl[12], 32, ntg, 2, 7, lane, acc);
      else if (q == 2)   mm(sBh, sBl, P.Wh[12], P.Wl[12], 32, ntg, 7, 12, lane, acc);
      else               mm(sBh, sBl, P.Wh[12], P.Wl[12], 32, ntg, 12, 16, lane, acc);
      if (q) *(f32x4*)&red[((((q - 1) << 1) | nt) << 8) | (lane << 2)] = acc;
      __syncthreads();
      if (!q) {
        #pragma unroll
        for (int j = 0; j < 3; ++j) acc += *(f32x4*)&red[(((j << 1) | nt) << 8) | (lane << 2)];
        const int col = (g << 5) | (nt << 4) | (lane & 15);
        const float b = P.bhm[col];
        const int rb = r0 + ((lane >> 4) << 2);
        float zv[4], hv[4];
        #pragma unroll
        for (int i = 0; i < 4; ++i) {
          const int idx = ((rb + i) << 9) | col;
          llc_ld1(zv[i], &P.zM[idx]); llc_ld1(hv[i], &Hm1[idx]);
        }
        vwait();
        #pragma unroll
        for (int i = 0; i < 4; ++i) {
          const int row = rb + i;
          const int idx = (row << 9) | col;
          const float hh = tanhf(acc[i] + b);
          const float hnew = (1.f - zv[i]) * hv[i] + zv[i] * hh;
          llc_st1(&Hcur[idx], hnew);
          P.out[((((size_t)row << 8) | t) << 9) | col] = hnew;   // normal store
        }
      }
    }
    gbar(P.cnt, stripe, ph);
  }
}

__global__ __launch_bounds__(256)
void initk(float* h1, float* h2, float* n, unsigned* cnt) {
  const int i = blockIdx.x * 256 + threadIdx.x;
  h1[i] = 0.f; h2[i] = 0.f; n[i] = 0.f;
  if (blockIdx.x == 0) cnt[threadIdx.x] = 0u;
}

__global__ __launch_bounds__(256)
void finalize(const float* __restrict__ hT, const float* __restrict__ nT,
              float* __restrict__ oh, float* __restrict__ on) {
  const int i = blockIdx.x * 256 + threadIdx.x;
  float a, b;
  llc_ld1(a, &hT[i]); llc_ld1(b, &nT[i]);
  vwait();
  oh[i] = a; on[i] = b;
}

extern "C" void kernel_launch(void* const* d_in, const int* in_sizes, int n_in,
                              void* d_out, int out_size, void* d_ws, size_t ws_size,
                              hipStream_t stream)
{
  (void)in_sizes; (void)n_in; (void)out_size; (void)ws_size;

  unsigned* cnt = (unsigned*)d_ws;          // 16 stripe counters, 64B apart
  float* w = (float*)d_ws + 256;
  const int S = Bsz * Hd;                   // 131072

  KP P{};
  P.x   = (const float*)d_in[0];
  P.ba  = (const float*)d_in[3];
  P.bna = (const float*)d_in[6];
  P.bma = (const float*)d_in[12];
  P.bm  = (const float*)d_in[15];
  P.bhm = (const float*)d_in[18];
  P.Hb0 = w;          P.Hb1 = w + S;      P.Hb2 = w + 2 * S;
  P.Nst = w + 3 * S;  P.zA  = w + 4 * S;  P.NrA = w + 5 * S;
  P.s1  = w + 6 * S;  P.score = w + 7 * S; P.mbuf = w + 8 * S;
  P.zM  = w + 9 * S;  P.mrM = w + 10 * S;
  P.out = (float*)d_out;
  P.cnt = cnt;
  float* out_hT = P.out + (size_t)Bsz * Tseq * Hd;
  float* out_NT = out_hT + S;

  // packed weights after fp32 scratch
  short* wpk = (short*)(w + 11 * S);
  const int widx[13] = {1, 2, 4, 5, 7, 8, 9, 10, 11, 13, 14, 16, 17};
  const int wK[13]   = {512, 512, 512, 512, 512, 512, 512, 512, 512, 64, 512, 64, 512};
  const int wN[13]   = {1024, 1024, 512, 512, 512, 512, 512, 512, 512, 1024, 1024, 512, 512};
  {
    size_t off = 0;
    for (int i = 0; i < 13; ++i) {
      const size_t sz = (size_t)wK[i] * wN[i];
      P.Wh[i] = wpk + off; off += sz;
      P.Wl[i] = wpk + off; off += sz;
    }
  }
  for (int i = 0; i < 13; ++i) {
    dim3 gg(wN[i] / 256, wK[i] / 32);
    prepack<<<gg, 256, 0, stream>>>((const float*)d_in[widx[i]],
                                    (short*)P.Wh[i], (short*)P.Wl[i], wN[i]);
  }

  initk<<<S / 256, 256, 0, stream>>>(P.Hb1, P.Hb2, P.Nst, cnt);

  dtgru<<<NBLK, NTHR, 0, stream>>>(P);

  finalize<<<S / 256, 256, 0, stream>>>(P.Hb0 /* (Tseq-1)%3 == 0 */, P.Nst,
                                        out_hT, out_NT);
}